// Round 1
// baseline (544.903 us; speedup 1.0000x reference)
//
#include <hip/hip_runtime.h>
#include <hip/hip_bf16.h>

#define VN 3129
#define DN 768
#define BN 2048

// ws layout (4-byte words):
//   n2      [0, 3136)          : float, row norms^2 of sim
//   part1   [3136, 7232)       : float, per-block logaddexp partials (grid 2048)
//   part2   [7232, 9280)       : float, per-row pred*semantic partials
//   argbest [9280 .. +3129*2)  : u64 packed (sortable_score<<32 | j)
static const int W_N2  = 0;
static const int W_P1  = 3136;
static const int W_P2  = 7232;
static const int W_ARG = 9280;
static const int INIT_WORDS = 9280 + VN * 2;   // 15538
static const int GRID_LOGEXP = 2048;

__global__ __launch_bounds__(256) void k_init(unsigned int* ws) {
    int idx = blockIdx.x * 256 + threadIdx.x;
    for (int i = idx; i < INIT_WORDS; i += gridDim.x * 256) ws[i] = 0u;
}

__global__ __launch_bounds__(256) void k_logexp(const float* __restrict__ pred,
                                                float* __restrict__ part1) {
    int tid = threadIdx.x;
    const float4* p4 = (const float4*)pred;
    const int n4 = BN * VN / 4;  // 1,602,048
    float acc = 0.f;
    for (int i = blockIdx.x * 256 + tid; i < n4; i += gridDim.x * 256) {
        float4 v = p4[i];
        acc += fmaxf(v.x, 0.f) + log1pf(__expf(-fabsf(v.x)));
        acc += fmaxf(v.y, 0.f) + log1pf(__expf(-fabsf(v.y)));
        acc += fmaxf(v.z, 0.f) + log1pf(__expf(-fabsf(v.z)));
        acc += fmaxf(v.w, 0.f) + log1pf(__expf(-fabsf(v.w)));
    }
    for (int off = 32; off; off >>= 1) acc += __shfl_down(acc, off);
    __shared__ float wsum[4];
    int lane = tid & 63, wid = tid >> 6;
    if (lane == 0) wsum[wid] = acc;
    __syncthreads();
    if (tid == 0) part1[blockIdx.x] = wsum[0] + wsum[1] + wsum[2] + wsum[3];
}

// PASS 0: accumulate n2[i] += sum_j sim(i,j)^2
// PASS 1: argbest[i] = max over j != i of packed(score, j), score = sim/(n_i*n_j+1e-8)
template <int PASS>
__global__ __launch_bounds__(256) void k_gemm(const float* __restrict__ E,
                                              float* __restrict__ n2,
                                              unsigned long long* __restrict__ argbest) {
    __shared__ float As[16][132];
    __shared__ float Bs[16][132];
    const int tid = threadIdx.x;
    const int tx = tid & 15, ty = tid >> 4;
    const int i0 = blockIdx.y * 128, j0 = blockIdx.x * 128;
    float acc[8][8] = {};

    for (int k0 = 0; k0 < DN; k0 += 16) {
#pragma unroll
        for (int h = 0; h < 2; ++h) {
            int f = tid + h * 256;
            int r = f >> 2;
            int kq = (f & 3) << 2;
            int gi = i0 + r;
            float4 va = make_float4(0.f, 0.f, 0.f, 0.f);
            if (gi < VN) va = *(const float4*)(E + gi * DN + k0 + kq);
            As[kq + 0][r] = va.x; As[kq + 1][r] = va.y;
            As[kq + 2][r] = va.z; As[kq + 3][r] = va.w;
            int gj = j0 + r;
            float4 vb = make_float4(0.f, 0.f, 0.f, 0.f);
            if (gj < VN) vb = *(const float4*)(E + gj * DN + k0 + kq);
            Bs[kq + 0][r] = vb.x; Bs[kq + 1][r] = vb.y;
            Bs[kq + 2][r] = vb.z; Bs[kq + 3][r] = vb.w;
        }
        __syncthreads();
#pragma unroll
        for (int k = 0; k < 16; ++k) {
            float a[8], b[8];
            *(float4*)&a[0] = *(const float4*)&As[k][ty * 8];
            *(float4*)&a[4] = *(const float4*)&As[k][ty * 8 + 4];
            *(float4*)&b[0] = *(const float4*)&Bs[k][tx * 8];
            *(float4*)&b[4] = *(const float4*)&Bs[k][tx * 8 + 4];
#pragma unroll
            for (int m = 0; m < 8; ++m)
#pragma unroll
                for (int n = 0; n < 8; ++n)
                    acc[m][n] = fmaf(a[m], b[n], acc[m][n]);
        }
        __syncthreads();
    }

    if (PASS == 0) {
        __shared__ float nrow[128];
        if (tid < 128) nrow[tid] = 0.f;
        __syncthreads();
#pragma unroll
        for (int m = 0; m < 8; ++m) {
            float s = 0.f;
#pragma unroll
            for (int n = 0; n < 8; ++n) s += acc[m][n] * acc[m][n];
            atomicAdd(&nrow[ty * 8 + m], s);   // padded j (>=VN) contributed 0
        }
        __syncthreads();
        if (tid < 128 && i0 + tid < VN) atomicAdd(&n2[i0 + tid], nrow[tid]);
    } else {
        __shared__ unsigned long long brow[128];
        if (tid < 128) brow[tid] = 0ull;
        __syncthreads();
        float njv[8];
#pragma unroll
        for (int n = 0; n < 8; ++n) {
            int j = j0 + tx * 8 + n;
            njv[n] = (j < VN) ? sqrtf(n2[j]) : 0.f;
        }
#pragma unroll
        for (int m = 0; m < 8; ++m) {
            int i = i0 + ty * 8 + m;
            float ni = (i < VN) ? sqrtf(n2[i]) : 0.f;
            unsigned long long best = 0ull;
#pragma unroll
            for (int n = 0; n < 8; ++n) {
                int j = j0 + tx * 8 + n;
                if (j < VN && j != i) {
                    float s = acc[m][n] / (ni * njv[n] + 1e-8f);
                    unsigned u = __float_as_uint(s);
                    u = (u & 0x80000000u) ? ~u : (u | 0x80000000u);
                    unsigned long long key =
                        ((unsigned long long)u << 32) | (unsigned)j;
                    if (key > best) best = key;
                }
            }
            atomicMax(&brow[ty * 8 + m], best);
        }
        __syncthreads();
        if (tid < 128 && i0 + tid < VN) atomicMax(&argbest[i0 + tid], brow[tid]);
    }
}

// per row: gather nonzero labels, dedupe targets with numpy last-write-wins
// (larger g wins), dot with prediction at the mapped columns.
__global__ __launch_bounds__(256) void k_scatter(const float* __restrict__ pred,
                                                 const float* __restrict__ label,
                                                 const unsigned long long* __restrict__ argbest,
                                                 float* __restrict__ part2) {
    int i = blockIdx.x;
    int tid = threadIdx.x;
    __shared__ int cnt;
    __shared__ unsigned short gs[256];
    __shared__ unsigned short ts[256];
    __shared__ float ls[256];
    if (tid == 0) cnt = 0;
    __syncthreads();
    const float* lrow = label + i * VN;
    for (int g = tid; g < VN; g += 256) {
        float l = lrow[g];
        if (l != 0.f) {
            int p = atomicAdd(&cnt, 1);
            if (p < 256) {
                gs[p] = (unsigned short)g;
                ls[p] = l;
                ts[p] = (unsigned short)(argbest[g] & 0xFFFFFFFFull);
            }
        }
    }
    __syncthreads();
    int m = min(cnt, 256);
    float contrib = 0.f;
    for (int e = tid; e < m; e += 256) {
        bool keep = true;
        for (int o = 0; o < m; ++o)
            if (ts[o] == ts[e] && gs[o] > gs[e]) keep = false;
        if (keep) contrib += pred[i * VN + ts[e]] * ls[e];
    }
    for (int off = 32; off; off >>= 1) contrib += __shfl_down(contrib, off);
    __shared__ float wsum[4];
    int lane = tid & 63, wid = tid >> 6;
    if (lane == 0) wsum[wid] = contrib;
    __syncthreads();
    if (tid == 0) part2[i] = wsum[0] + wsum[1] + wsum[2] + wsum[3];
}

__global__ __launch_bounds__(256) void k_final(const float* __restrict__ part1,
                                               const float* __restrict__ part2,
                                               float* __restrict__ out) {
    int tid = threadIdx.x;
    double acc = 0.0;
    for (int i = tid; i < GRID_LOGEXP; i += 256) acc += (double)part1[i];
    for (int i = tid; i < BN; i += 256) acc -= (double)part2[i];
    __shared__ double red[256];
    red[tid] = acc;
    __syncthreads();
    for (int s = 128; s; s >>= 1) {
        if (tid < s) red[tid] += red[tid + s];
        __syncthreads();
    }
    if (tid == 0) out[0] = (float)(red[0] / (double)BN);
}

extern "C" void kernel_launch(void* const* d_in, const int* in_sizes, int n_in,
                              void* d_out, int out_size, void* d_ws, size_t ws_size,
                              hipStream_t stream) {
    (void)in_sizes; (void)n_in; (void)out_size; (void)ws_size;
    const float* pred  = (const float*)d_in[0];
    const float* label = (const float*)d_in[1];
    const float* E     = (const float*)d_in[2];
    float* out = (float*)d_out;
    float* ws  = (float*)d_ws;

    float* n2    = ws + W_N2;
    float* part1 = ws + W_P1;
    float* part2 = ws + W_P2;
    unsigned long long* argbest = (unsigned long long*)(ws + W_ARG);

    k_init<<<61, 256, 0, stream>>>((unsigned int*)ws);
    k_logexp<<<GRID_LOGEXP, 256, 0, stream>>>(pred, part1);
    dim3 g((VN + 127) / 128, (VN + 127) / 128);  // 25 x 25
    k_gemm<0><<<g, 256, 0, stream>>>(E, n2, argbest);
    k_gemm<1><<<g, 256, 0, stream>>>(E, n2, argbest);
    k_scatter<<<BN, 256, 0, stream>>>(pred, label, argbest, part2);
    k_final<<<1, 256, 0, stream>>>(part1, part2, out);
}

// Round 2
// 121.475 us; speedup vs baseline: 4.4857x; 4.4857x over previous
//
#include <hip/hip_runtime.h>
#include <hip/hip_bf16.h>

#define VN 3129
#define DN 768
#define BN 2048
#define NT 3200              // VN padded to 25*128

typedef __attribute__((ext_vector_type(8))) short bf16x8;
typedef __attribute__((ext_vector_type(4))) float f32x4;

// ---------------- fast path ws layout (bytes) ----------------
// Eb      [0, 4915200)            : bf16 E padded to NT rows
// n2      [4915200, +12800)       : float[3200]
// argbest [4928000, +25600)       : u64[3200]
// part1   [4953600, +8192)        : float[2048]
// part2   [4961792, +8192)        : float[2048]
static const size_t WB_EB  = 0;
static const size_t WB_N2  = 4915200;
static const size_t WB_ARG = 4928000;
static const size_t WB_P1  = 4953600;
static const size_t WB_P2  = 4961792;
static const size_t WS_NEEDED = 4969984;
// zero region: everything after Eb = 54784 bytes = 13696 words
static const int ZERO_WORDS = 13696;

static const int GRID_LOGEXP = 2048;

__global__ __launch_bounds__(256) void k_zero(unsigned int* p, int nwords) {
    int idx = blockIdx.x * 256 + threadIdx.x;
    for (int i = idx; i < nwords; i += gridDim.x * 256) p[i] = 0u;
}

__global__ __launch_bounds__(256) void k_prep(const float* __restrict__ E,
                                              unsigned short* __restrict__ Eb) {
    int chunk = blockIdx.x * 256 + threadIdx.x;   // one chunk = 8 elements
    const int nchunks = NT * DN / 8;              // 307200
    if (chunk >= nchunks) return;
    int row = chunk / (DN / 8);
    int cc = (chunk % (DN / 8)) * 8;
    unsigned short out[8];
    if (row < VN) {
        const float* src = E + (size_t)row * DN + cc;
        float4 a = *(const float4*)src;
        float4 b = *(const float4*)(src + 4);
        float v[8] = {a.x, a.y, a.z, a.w, b.x, b.y, b.z, b.w};
#pragma unroll
        for (int t = 0; t < 8; ++t) {
            unsigned u = __float_as_uint(v[t]);
            u += 0x7FFFu + ((u >> 16) & 1u);      // RNE
            out[t] = (unsigned short)(u >> 16);
        }
    } else {
#pragma unroll
        for (int t = 0; t < 8; ++t) out[t] = 0;
    }
    *(uint4*)(Eb + (size_t)chunk * 8) = *(const uint4*)out;
}

__global__ __launch_bounds__(256) void k_logexp(const float* __restrict__ pred,
                                                float* __restrict__ part1) {
    int tid = threadIdx.x;
    const float4* p4 = (const float4*)pred;
    const int n4 = BN * VN / 4;
    float acc = 0.f;
    for (int i = blockIdx.x * 256 + tid; i < n4; i += gridDim.x * 256) {
        float4 v = p4[i];
        acc += fmaxf(v.x, 0.f) + log1pf(__expf(-fabsf(v.x)));
        acc += fmaxf(v.y, 0.f) + log1pf(__expf(-fabsf(v.y)));
        acc += fmaxf(v.z, 0.f) + log1pf(__expf(-fabsf(v.z)));
        acc += fmaxf(v.w, 0.f) + log1pf(__expf(-fabsf(v.w)));
    }
    for (int off = 32; off; off >>= 1) acc += __shfl_down(acc, off);
    __shared__ float wsum[4];
    int lane = tid & 63, wid = tid >> 6;
    if (lane == 0) wsum[wid] = acc;
    __syncthreads();
    if (tid == 0) part1[blockIdx.x] = wsum[0] + wsum[1] + wsum[2] + wsum[3];
}

// ---------------- MFMA Gram kernel ----------------
// PASS 0: n2[i] += sum_j sim(i,j)^2
// PASS 1: argbest[i] = max_j!=i packed(score, j), score = sim/(n_i*n_j+1e-8)
template <int PASS>
__global__ __launch_bounds__(256) void k_mgemm(const unsigned short* __restrict__ Eb,
                                               float* __restrict__ n2,
                                               unsigned long long* __restrict__ argbest) {
    __shared__ __align__(16) unsigned short As[128][72];
    __shared__ __align__(16) unsigned short Bs[128][72];
    const int tid = threadIdx.x;
    const int lane = tid & 63;
    const int w = tid >> 6;
    const int wr = w >> 1, wc = w & 1;
    const int i0 = blockIdx.y * 128, j0 = blockIdx.x * 128;
    const int sr = tid >> 3, sc = (tid & 7) * 8;

    f32x4 acc[4][4] = {};

    for (int k0 = 0; k0 < DN; k0 += 64) {
#pragma unroll
        for (int q = 0; q < 4; ++q) {
            int r = sr + 32 * q;
            uint4 va = *(const uint4*)(Eb + (size_t)(i0 + r) * DN + k0 + sc);
            *(uint4*)&As[r][sc] = va;
            uint4 vb = *(const uint4*)(Eb + (size_t)(j0 + r) * DN + k0 + sc);
            *(uint4*)&Bs[r][sc] = vb;
        }
        __syncthreads();
#pragma unroll
        for (int ks = 0; ks < 2; ++ks) {
            bf16x8 af[4], bfr[4];
            const int rrow = lane & 15;
            const int kcol = ks * 32 + (lane >> 4) * 8;
#pragma unroll
            for (int m = 0; m < 4; ++m)
                af[m] = *(const bf16x8*)&As[wr * 64 + m * 16 + rrow][kcol];
#pragma unroll
            for (int n = 0; n < 4; ++n)
                bfr[n] = *(const bf16x8*)&Bs[wc * 64 + n * 16 + rrow][kcol];
#pragma unroll
            for (int m = 0; m < 4; ++m)
#pragma unroll
                for (int n = 0; n < 4; ++n)
                    acc[m][n] = __builtin_amdgcn_mfma_f32_16x16x32_bf16(
                        af[m], bfr[n], acc[m][n], 0, 0, 0);
        }
        __syncthreads();
    }

    // C/D layout: col = lane&15, row = (lane>>4)*4 + reg
    if (PASS == 0) {
        __shared__ float nrow[128];
        if (tid < 128) nrow[tid] = 0.f;
        __syncthreads();
#pragma unroll
        for (int m = 0; m < 4; ++m)
#pragma unroll
            for (int i = 0; i < 4; ++i) {
                float s = 0.f;
#pragma unroll
                for (int n = 0; n < 4; ++n) s += acc[m][n][i] * acc[m][n][i];
                for (int off = 1; off < 16; off <<= 1) s += __shfl_xor(s, off);
                if ((lane & 15) == 0)
                    atomicAdd(&nrow[wr * 64 + m * 16 + (lane >> 4) * 4 + i], s);
            }
        __syncthreads();
        if (tid < 128) atomicAdd(&n2[i0 + tid], nrow[tid]);
    } else {
        __shared__ unsigned long long brow[128];
        if (tid < 128) brow[tid] = 0ull;
        __syncthreads();
        float njv[4];
#pragma unroll
        for (int n = 0; n < 4; ++n)
            njv[n] = sqrtf(n2[j0 + wc * 64 + n * 16 + (lane & 15)]);
#pragma unroll
        for (int m = 0; m < 4; ++m)
#pragma unroll
            for (int i = 0; i < 4; ++i) {
                int ri = i0 + wr * 64 + m * 16 + (lane >> 4) * 4 + i;
                float ni = sqrtf(n2[ri]);
                unsigned long long best = 0ull;
#pragma unroll
                for (int n = 0; n < 4; ++n) {
                    int jc = j0 + wc * 64 + n * 16 + (lane & 15);
                    if (jc < VN && jc != ri) {
                        float s = acc[m][n][i] / (ni * njv[n] + 1e-8f);
                        unsigned u = __float_as_uint(s);
                        u = (u & 0x80000000u) ? ~u : (u | 0x80000000u);
                        unsigned long long key =
                            ((unsigned long long)u << 32) | (unsigned)jc;
                        if (key > best) best = key;
                    }
                }
                for (int off = 1; off < 16; off <<= 1) {
                    unsigned long long o = __shfl_xor(best, off);
                    if (o > best) best = o;
                }
                if ((lane & 15) == 0)
                    atomicMax(&brow[wr * 64 + m * 16 + (lane >> 4) * 4 + i], best);
            }
        __syncthreads();
        if (tid < 128) atomicMax(&argbest[i0 + tid], brow[tid]);
    }
}

// ---------------- fallback fp32 Gram (verified R1 path) ----------------
template <int PASS>
__global__ __launch_bounds__(256) void k_gemm(const float* __restrict__ E,
                                              float* __restrict__ n2,
                                              unsigned long long* __restrict__ argbest) {
    __shared__ float As[16][132];
    __shared__ float Bs[16][132];
    const int tid = threadIdx.x;
    const int tx = tid & 15, ty = tid >> 4;
    const int i0 = blockIdx.y * 128, j0 = blockIdx.x * 128;
    float acc[8][8] = {};

    for (int k0 = 0; k0 < DN; k0 += 16) {
#pragma unroll
        for (int h = 0; h < 2; ++h) {
            int f = tid + h * 256;
            int r = f >> 2;
            int kq = (f & 3) << 2;
            int gi = i0 + r;
            float4 va = make_float4(0.f, 0.f, 0.f, 0.f);
            if (gi < VN) va = *(const float4*)(E + gi * DN + k0 + kq);
            As[kq + 0][r] = va.x; As[kq + 1][r] = va.y;
            As[kq + 2][r] = va.z; As[kq + 3][r] = va.w;
            int gj = j0 + r;
            float4 vb = make_float4(0.f, 0.f, 0.f, 0.f);
            if (gj < VN) vb = *(const float4*)(E + gj * DN + k0 + kq);
            Bs[kq + 0][r] = vb.x; Bs[kq + 1][r] = vb.y;
            Bs[kq + 2][r] = vb.z; Bs[kq + 3][r] = vb.w;
        }
        __syncthreads();
#pragma unroll
        for (int k = 0; k < 16; ++k) {
            float a[8], b[8];
            *(float4*)&a[0] = *(const float4*)&As[k][ty * 8];
            *(float4*)&a[4] = *(const float4*)&As[k][ty * 8 + 4];
            *(float4*)&b[0] = *(const float4*)&Bs[k][tx * 8];
            *(float4*)&b[4] = *(const float4*)&Bs[k][tx * 8 + 4];
#pragma unroll
            for (int m = 0; m < 8; ++m)
#pragma unroll
                for (int n = 0; n < 8; ++n)
                    acc[m][n] = fmaf(a[m], b[n], acc[m][n]);
        }
        __syncthreads();
    }

    if (PASS == 0) {
        __shared__ float nrow[128];
        if (tid < 128) nrow[tid] = 0.f;
        __syncthreads();
#pragma unroll
        for (int m = 0; m < 8; ++m) {
            float s = 0.f;
#pragma unroll
            for (int n = 0; n < 8; ++n) s += acc[m][n] * acc[m][n];
            atomicAdd(&nrow[ty * 8 + m], s);
        }
        __syncthreads();
        if (tid < 128 && i0 + tid < VN) atomicAdd(&n2[i0 + tid], nrow[tid]);
    } else {
        __shared__ unsigned long long brow[128];
        if (tid < 128) brow[tid] = 0ull;
        __syncthreads();
        float njv[8];
#pragma unroll
        for (int n = 0; n < 8; ++n) {
            int j = j0 + tx * 8 + n;
            njv[n] = (j < VN) ? sqrtf(n2[j]) : 0.f;
        }
#pragma unroll
        for (int m = 0; m < 8; ++m) {
            int i = i0 + ty * 8 + m;
            float ni = (i < VN) ? sqrtf(n2[i]) : 0.f;
            unsigned long long best = 0ull;
#pragma unroll
            for (int n = 0; n < 8; ++n) {
                int j = j0 + tx * 8 + n;
                if (j < VN && j != i) {
                    float s = acc[m][n] / (ni * njv[n] + 1e-8f);
                    unsigned u = __float_as_uint(s);
                    u = (u & 0x80000000u) ? ~u : (u | 0x80000000u);
                    unsigned long long key =
                        ((unsigned long long)u << 32) | (unsigned)j;
                    if (key > best) best = key;
                }
            }
            atomicMax(&brow[ty * 8 + m], best);
        }
        __syncthreads();
        if (tid < 128 && i0 + tid < VN) atomicMax(&argbest[i0 + tid], brow[tid]);
    }
}

// ---------------- scatter + finalize ----------------
__global__ __launch_bounds__(256) void k_scatter(const float* __restrict__ pred,
                                                 const float* __restrict__ label,
                                                 const unsigned long long* __restrict__ argbest,
                                                 float* __restrict__ part2) {
    int i = blockIdx.x;
    int tid = threadIdx.x;
    __shared__ int cnt;
    __shared__ unsigned short gs[256];
    __shared__ unsigned short ts[256];
    __shared__ float ls[256];
    if (tid == 0) cnt = 0;
    __syncthreads();
    const float* lrow = label + (size_t)i * VN;
    for (int g = tid; g < VN; g += 256) {
        float l = lrow[g];
        if (l != 0.f) {
            int p = atomicAdd(&cnt, 1);
            if (p < 256) {
                gs[p] = (unsigned short)g;
                ls[p] = l;
                ts[p] = (unsigned short)(argbest[g] & 0xFFFFFFFFull);
            }
        }
    }
    __syncthreads();
    int m = min(cnt, 256);
    float contrib = 0.f;
    for (int e = tid; e < m; e += 256) {
        bool keep = true;
        for (int o = 0; o < m; ++o)
            if (ts[o] == ts[e] && gs[o] > gs[e]) keep = false;
        if (keep) contrib += pred[(size_t)i * VN + ts[e]] * ls[e];
    }
    for (int off = 32; off; off >>= 1) contrib += __shfl_down(contrib, off);
    __shared__ float wsum[4];
    int lane = tid & 63, wid = tid >> 6;
    if (lane == 0) wsum[wid] = contrib;
    __syncthreads();
    if (tid == 0) part2[i] = wsum[0] + wsum[1] + wsum[2] + wsum[3];
}

__global__ __launch_bounds__(256) void k_final(const float* __restrict__ part1,
                                               const float* __restrict__ part2,
                                               float* __restrict__ out) {
    int tid = threadIdx.x;
    double acc = 0.0;
    for (int i = tid; i < GRID_LOGEXP; i += 256) acc += (double)part1[i];
    for (int i = tid; i < BN; i += 256) acc -= (double)part2[i];
    __shared__ double red[256];
    red[tid] = acc;
    __syncthreads();
    for (int s = 128; s; s >>= 1) {
        if (tid < s) red[tid] += red[tid + s];
        __syncthreads();
    }
    if (tid == 0) out[0] = (float)(red[0] / (double)BN);
}

extern "C" void kernel_launch(void* const* d_in, const int* in_sizes, int n_in,
                              void* d_out, int out_size, void* d_ws, size_t ws_size,
                              hipStream_t stream) {
    (void)in_sizes; (void)n_in; (void)out_size;
    const float* pred  = (const float*)d_in[0];
    const float* label = (const float*)d_in[1];
    const float* E     = (const float*)d_in[2];
    float* out = (float*)d_out;
    char* wsb = (char*)d_ws;

    if (ws_size >= WS_NEEDED) {
        unsigned short* Eb = (unsigned short*)(wsb + WB_EB);
        float* n2    = (float*)(wsb + WB_N2);
        unsigned long long* argbest = (unsigned long long*)(wsb + WB_ARG);
        float* part1 = (float*)(wsb + WB_P1);
        float* part2 = (float*)(wsb + WB_P2);

        k_zero<<<16, 256, 0, stream>>>((unsigned int*)(wsb + WB_N2), ZERO_WORDS);
        k_prep<<<NT * DN / 8 / 256, 256, 0, stream>>>(E, Eb);
        k_logexp<<<GRID_LOGEXP, 256, 0, stream>>>(pred, part1);
        dim3 g(NT / 128, NT / 128);  // 25 x 25
        k_mgemm<0><<<g, 256, 0, stream>>>(Eb, n2, argbest);
        k_mgemm<1><<<g, 256, 0, stream>>>(Eb, n2, argbest);
        k_scatter<<<BN, 256, 0, stream>>>(pred, label, argbest, part2);
        k_final<<<1, 256, 0, stream>>>(part1, part2, out);
    } else {
        // fallback: verified fp32 path, small ws
        float* ws = (float*)d_ws;
        float* n2    = ws;
        float* part1 = ws + 3136;
        float* part2 = ws + 7232;
        unsigned long long* argbest = (unsigned long long*)(ws + 9280);
        k_zero<<<16, 256, 0, stream>>>((unsigned int*)ws, 9280 + VN * 2);
        k_logexp<<<GRID_LOGEXP, 256, 0, stream>>>(pred, part1);
        dim3 g((VN + 127) / 128, (VN + 127) / 128);
        k_gemm<0><<<g, 256, 0, stream>>>(E, n2, argbest);
        k_gemm<1><<<g, 256, 0, stream>>>(E, n2, argbest);
        k_scatter<<<BN, 256, 0, stream>>>(pred, label, argbest, part2);
        k_final<<<1, 256, 0, stream>>>(part1, part2, out);
    }
}

// Round 3
// 90.459 us; speedup vs baseline: 6.0237x; 1.3429x over previous
//
#include <hip/hip_runtime.h>
#include <hip/hip_bf16.h>

#define VN 3129
#define DN 768
#define BN 2048
#define NT 3200              // VN padded to 25*128
#define NB 25                // tile blocks per side
#define NTRI 325             // NB*(NB+1)/2

typedef __attribute__((ext_vector_type(8))) short bf16x8;
typedef __attribute__((ext_vector_type(4))) float f32x4;

typedef __attribute__((address_space(3))) void as3_void;
typedef __attribute__((address_space(1))) const void as1_cvoid;

__device__ __forceinline__ void gload16(const void* g, void* l) {
    __builtin_amdgcn_global_load_lds((as1_cvoid*)g, (as3_void*)l, 16, 0, 0);
}

// ---------------- fast path ws layout (bytes) ----------------
// Eb      [0, 4915200)             : bf16 E padded to NT rows
// simT    [4915200, +10649600)     : bf16 tiles, 325 x 128 x 128, lane-packed
// n2      [15564800, +12800)       : float[3200]
// argbest [15577600, +25600)       : u64[3200]
// part1   [15603200, +8192)        : float[2048]
// part2   [15611392, +8192)        : float[2048]
static const size_t WB_EB  = 0;
static const size_t WB_SIM = 4915200;
static const size_t WB_N2  = 15564800;
static const size_t WB_ARG = 15577600;
static const size_t WB_P1  = 15603200;
static const size_t WB_P2  = 15611392;
static const size_t WS_NEEDED3 = 15619584;
static const int ZERO_WORDS3 = 9600;      // n2 + argbest contiguous

// ---------------- mid fallback (R2) ws layout ----------------
static const size_t W2_EB  = 0;
static const size_t W2_N2  = 4915200;
static const size_t W2_ARG = 4928000;
static const size_t W2_P1  = 4953600;
static const size_t W2_P2  = 4961792;
static const size_t WS_NEEDED2 = 4969984;
static const int ZERO_WORDS2 = 13696;

static const int GRID_LOGEXP = 2048;

__global__ __launch_bounds__(256) void k_zero(unsigned int* p, int nwords) {
    int idx = blockIdx.x * 256 + threadIdx.x;
    for (int i = idx; i < nwords; i += gridDim.x * 256) p[i] = 0u;
}

__global__ __launch_bounds__(256) void k_prep(const float* __restrict__ E,
                                              unsigned short* __restrict__ Eb) {
    int chunk = blockIdx.x * 256 + threadIdx.x;   // one chunk = 8 elements
    const int nchunks = NT * DN / 8;              // 307200
    if (chunk >= nchunks) return;
    int row = chunk / (DN / 8);
    int cc = (chunk % (DN / 8)) * 8;
    unsigned short out[8];
    if (row < VN) {
        const float* src = E + (size_t)row * DN + cc;
        float4 a = *(const float4*)src;
        float4 b = *(const float4*)(src + 4);
        float v[8] = {a.x, a.y, a.z, a.w, b.x, b.y, b.z, b.w};
#pragma unroll
        for (int t = 0; t < 8; ++t) {
            unsigned u = __float_as_uint(v[t]);
            u += 0x7FFFu + ((u >> 16) & 1u);      // RNE
            out[t] = (unsigned short)(u >> 16);
        }
    } else {
#pragma unroll
        for (int t = 0; t < 8; ++t) out[t] = 0;
    }
    *(uint4*)(Eb + (size_t)chunk * 8) = *(const uint4*)out;
}

__global__ __launch_bounds__(256) void k_logexp(const float* __restrict__ pred,
                                                float* __restrict__ part1) {
    int tid = threadIdx.x;
    const float4* p4 = (const float4*)pred;
    const int n4 = BN * VN / 4;
    float acc = 0.f;
    for (int i = blockIdx.x * 256 + tid; i < n4; i += gridDim.x * 256) {
        float4 v = p4[i];
        acc += fmaxf(v.x, 0.f) + log1pf(__expf(-fabsf(v.x)));
        acc += fmaxf(v.y, 0.f) + log1pf(__expf(-fabsf(v.y)));
        acc += fmaxf(v.z, 0.f) + log1pf(__expf(-fabsf(v.z)));
        acc += fmaxf(v.w, 0.f) + log1pf(__expf(-fabsf(v.w)));
    }
    for (int off = 32; off; off >>= 1) acc += __shfl_down(acc, off);
    __shared__ float wsum[4];
    int lane = tid & 63, wid = tid >> 6;
    if (lane == 0) wsum[wid] = acc;
    __syncthreads();
    if (tid == 0) part1[blockIdx.x] = wsum[0] + wsum[1] + wsum[2] + wsum[3];
}

// ---------------- fused symmetric Gram GEMM ----------------
// One block per upper-triangle tile (bi<=bj). Computes sim tile via MFMA,
// accumulates n2 row/col sums, stores bf16 sim tile in lane-packed layout.
__global__ __launch_bounds__(256) void k_gsym(const unsigned short* __restrict__ Eb,
                                              float* __restrict__ n2,
                                              unsigned short* __restrict__ simT) {
    __shared__ __align__(16) unsigned short As[128 * 64];
    __shared__ __align__(16) unsigned short Bs[128 * 64];
    const int tid = threadIdx.x;
    const int lane = tid & 63;
    const int w = tid >> 6;
    const int wr = w >> 1, wc = w & 1;

    int t = blockIdx.x, bi = 0, rem = t;
    while (rem >= NB - bi) { rem -= NB - bi; ++bi; }
    const int bj = bi + rem;
    const int i0 = bi * 128, j0 = bj * 128;

    // staging geometry: 16 chunks of 1024B per tile; wave w owns chunks w*4..w*4+3
    // lane l -> row = ci*8 + (l>>3); source col pre-swizzled: 8*((l&7)^(l>>3))
    const int srow = lane >> 3;
    const int scol = 8 * ((lane & 7) ^ (lane >> 3));

    f32x4 acc[4][4] = {};

    for (int k0 = 0; k0 < DN; k0 += 64) {
#pragma unroll
        for (int q = 0; q < 4; ++q) {
            int ci = w * 4 + q;
            int row = ci * 8 + srow;
            gload16(Eb + (size_t)(i0 + row) * DN + k0 + scol, As + ci * 512);
            gload16(Eb + (size_t)(j0 + row) * DN + k0 + scol, Bs + ci * 512);
        }
        __syncthreads();
        const int rA = wr * 64 + (lane & 15);
        const int rB = wc * 64 + (lane & 15);
        const int swr = (lane & 7) << 4;
        const int kb = (lane >> 4) * 16;
#pragma unroll
        for (int ks = 0; ks < 2; ++ks) {
            const int cb = (kb + ks * 64) ^ swr;
            bf16x8 af[4], bfr[4];
#pragma unroll
            for (int m = 0; m < 4; ++m)
                af[m] = *(const bf16x8*)((const char*)As + (rA + m * 16) * 128 + cb);
#pragma unroll
            for (int n = 0; n < 4; ++n)
                bfr[n] = *(const bf16x8*)((const char*)Bs + (rB + n * 16) * 128 + cb);
#pragma unroll
            for (int m = 0; m < 4; ++m)
#pragma unroll
                for (int n = 0; n < 4; ++n)
                    acc[m][n] = __builtin_amdgcn_mfma_f32_16x16x32_bf16(
                        af[m], bfr[n], acc[m][n], 0, 0, 0);
        }
        __syncthreads();
    }

    // ---- n2 row sums (rows of bi-block) ----
    __shared__ float red[128];
    const int rr4 = (lane >> 4) * 4;
    if (tid < 128) red[tid] = 0.f;
    __syncthreads();
#pragma unroll
    for (int m = 0; m < 4; ++m)
#pragma unroll
        for (int i = 0; i < 4; ++i) {
            float s = 0.f;
#pragma unroll
            for (int n = 0; n < 4; ++n) { float x = acc[m][n][i]; s += x * x; }
            s += __shfl_xor(s, 1); s += __shfl_xor(s, 2);
            s += __shfl_xor(s, 4); s += __shfl_xor(s, 8);
            if ((lane & 15) == 0)
                atomicAdd(&red[wr * 64 + m * 16 + rr4 + i], s);
        }
    __syncthreads();
    if (tid < 128) atomicAdd(&n2[i0 + tid], red[tid]);
    // ---- n2 col sums (cols of bj-block), off-diagonal only ----
    if (bi != bj) {
        __syncthreads();
        if (tid < 128) red[tid] = 0.f;
        __syncthreads();
#pragma unroll
        for (int n = 0; n < 4; ++n) {
            float s = 0.f;
#pragma unroll
            for (int m = 0; m < 4; ++m)
#pragma unroll
                for (int i = 0; i < 4; ++i) { float x = acc[m][n][i]; s += x * x; }
            s += __shfl_xor(s, 16); s += __shfl_xor(s, 32);
            if (lane < 16)
                atomicAdd(&red[wc * 64 + n * 16 + lane], s);
        }
        __syncthreads();
        if (tid < 128) atomicAdd(&n2[j0 + tid], red[tid]);
    }

    // ---- store bf16 sim tile, lane-packed: tile[tid][v], v=(m*4+n)*4+i ----
    {
        unsigned short* dst = simT + (size_t)t * 16384 + (size_t)tid * 64;
        uint4 ov[8];
        unsigned* op = (unsigned*)ov;
#pragma unroll
        for (int m = 0; m < 4; ++m)
#pragma unroll
            for (int n = 0; n < 4; ++n)
#pragma unroll
                for (int ih = 0; ih < 2; ++ih) {
                    unsigned lo = __float_as_uint(acc[m][n][ih * 2]);
                    lo += 0x7FFFu + ((lo >> 16) & 1u);
                    unsigned hi = __float_as_uint(acc[m][n][ih * 2 + 1]);
                    hi += 0x7FFFu + ((hi >> 16) & 1u);
                    op[(m * 4 + n) * 2 + ih] = (lo >> 16) | (hi & 0xFFFF0000u);
                }
#pragma unroll
        for (int q = 0; q < 8; ++q) ((uint4*)dst)[q] = ov[q];
    }
}

// ---------------- argmax over stored sim tiles ----------------
__global__ __launch_bounds__(256) void k_argmax(const unsigned short* __restrict__ simT,
                                                const float* __restrict__ n2,
                                                unsigned long long* __restrict__ argbest) {
    const int tid = threadIdx.x, lane = tid & 63, w = tid >> 6;
    const int wr = w >> 1, wc = w & 1;
    int t = blockIdx.x, bi = 0, rem = t;
    while (rem >= NB - bi) { rem -= NB - bi; ++bi; }
    const int bj = bi + rem;
    const int i0 = bi * 128, j0 = bj * 128;

    __shared__ float ni_s[128], nj_s[128];
    __shared__ unsigned long long rbest[128], cbest[128];
    if (tid < 128) {
        ni_s[tid] = sqrtf(n2[i0 + tid]);
        nj_s[tid] = sqrtf(n2[j0 + tid]);
        rbest[tid] = 0ull; cbest[tid] = 0ull;
    }
    __syncthreads();

    const unsigned short* src = simT + (size_t)t * 16384 + (size_t)tid * 64;
    uint4 iv[8];
#pragma unroll
    for (int q = 0; q < 8; ++q) iv[q] = ((const uint4*)src)[q];
    const unsigned* ip = (const unsigned*)iv;

    const int rr4 = (lane >> 4) * 4;
    float niv[16]; int rg[16];
#pragma unroll
    for (int m = 0; m < 4; ++m)
#pragma unroll
        for (int i = 0; i < 4; ++i) {
            int rl = wr * 64 + m * 16 + rr4 + i;
            rg[m * 4 + i] = i0 + rl;
            niv[m * 4 + i] = ni_s[rl];
        }
    float njv[4]; int cg[4];
#pragma unroll
    for (int n = 0; n < 4; ++n) {
        int cl = wc * 64 + n * 16 + (lane & 15);
        cg[n] = j0 + cl;
        njv[n] = nj_s[cl];
    }

    // row side: candidates j in bj-block for rows i in bi-block
#pragma unroll
    for (int m = 0; m < 4; ++m)
#pragma unroll
        for (int i = 0; i < 4; ++i) {
            int ig = rg[m * 4 + i];
            unsigned long long best = 0ull;
#pragma unroll
            for (int n = 0; n < 4; ++n) {
                int jg = cg[n];
                if (jg < VN && jg != ig) {
                    unsigned wv = ip[(m * 4 + n) * 2 + (i >> 1)];
                    float v = __uint_as_float((i & 1) ? (wv & 0xFFFF0000u) : (wv << 16));
                    float sc = v / (niv[m * 4 + i] * njv[n] + 1e-8f);
                    unsigned u = __float_as_uint(sc);
                    u = (u & 0x80000000u) ? ~u : (u | 0x80000000u);
                    unsigned long long key = ((unsigned long long)u << 32) | (unsigned)jg;
                    if (key > best) best = key;
                }
            }
            unsigned long long o;
            o = __shfl_xor(best, 1); if (o > best) best = o;
            o = __shfl_xor(best, 2); if (o > best) best = o;
            o = __shfl_xor(best, 4); if (o > best) best = o;
            o = __shfl_xor(best, 8); if (o > best) best = o;
            if ((lane & 15) == 0)
                atomicMax(&rbest[wr * 64 + m * 16 + rr4 + i], best);
        }

    // col side: candidates i in bi-block for rows j in bj-block (symmetry)
    if (bi != bj) {
#pragma unroll
        for (int n = 0; n < 4; ++n) {
            int jg = cg[n];
            unsigned long long best = 0ull;
#pragma unroll
            for (int m = 0; m < 4; ++m)
#pragma unroll
                for (int i = 0; i < 4; ++i) {
                    int ig = rg[m * 4 + i];
                    if (ig < VN) {
                        unsigned wv = ip[(m * 4 + n) * 2 + (i >> 1)];
                        float v = __uint_as_float((i & 1) ? (wv & 0xFFFF0000u) : (wv << 16));
                        float sc = v / (niv[m * 4 + i] * njv[n] + 1e-8f);
                        unsigned u = __float_as_uint(sc);
                        u = (u & 0x80000000u) ? ~u : (u | 0x80000000u);
                        unsigned long long key = ((unsigned long long)u << 32) | (unsigned)ig;
                        if (key > best) best = key;
                    }
                }
            unsigned long long o;
            o = __shfl_xor(best, 16); if (o > best) best = o;
            o = __shfl_xor(best, 32); if (o > best) best = o;
            if (lane < 16)
                atomicMax(&cbest[wc * 64 + n * 16 + lane], best);
        }
    }
    __syncthreads();
    if (tid < 128) {
        unsigned long long rb = rbest[tid];
        if (rb) atomicMax(&argbest[i0 + tid], rb);
        if (bi != bj) {
            unsigned long long cb = cbest[tid];
            if (cb) atomicMax(&argbest[j0 + tid], cb);
        }
    }
}

// ---------------- mid fallback: R2 two-pass MFMA Gram ----------------
template <int PASS>
__global__ __launch_bounds__(256) void k_mgemm(const unsigned short* __restrict__ Eb,
                                               float* __restrict__ n2,
                                               unsigned long long* __restrict__ argbest) {
    __shared__ __align__(16) unsigned short As[128][72];
    __shared__ __align__(16) unsigned short Bs[128][72];
    const int tid = threadIdx.x;
    const int lane = tid & 63;
    const int w = tid >> 6;
    const int wr = w >> 1, wc = w & 1;
    const int i0 = blockIdx.y * 128, j0 = blockIdx.x * 128;
    const int sr = tid >> 3, sc = (tid & 7) * 8;

    f32x4 acc[4][4] = {};

    for (int k0 = 0; k0 < DN; k0 += 64) {
#pragma unroll
        for (int q = 0; q < 4; ++q) {
            int r = sr + 32 * q;
            uint4 va = *(const uint4*)(Eb + (size_t)(i0 + r) * DN + k0 + sc);
            *(uint4*)&As[r][sc] = va;
            uint4 vb = *(const uint4*)(Eb + (size_t)(j0 + r) * DN + k0 + sc);
            *(uint4*)&Bs[r][sc] = vb;
        }
        __syncthreads();
#pragma unroll
        for (int ks = 0; ks < 2; ++ks) {
            bf16x8 af[4], bfr[4];
            const int rrow = lane & 15;
            const int kcol = ks * 32 + (lane >> 4) * 8;
#pragma unroll
            for (int m = 0; m < 4; ++m)
                af[m] = *(const bf16x8*)&As[wr * 64 + m * 16 + rrow][kcol];
#pragma unroll
            for (int n = 0; n < 4; ++n)
                bfr[n] = *(const bf16x8*)&Bs[wc * 64 + n * 16 + rrow][kcol];
#pragma unroll
            for (int m = 0; m < 4; ++m)
#pragma unroll
                for (int n = 0; n < 4; ++n)
                    acc[m][n] = __builtin_amdgcn_mfma_f32_16x16x32_bf16(
                        af[m], bfr[n], acc[m][n], 0, 0, 0);
        }
        __syncthreads();
    }

    if (PASS == 0) {
        __shared__ float nrow[128];
        if (tid < 128) nrow[tid] = 0.f;
        __syncthreads();
#pragma unroll
        for (int m = 0; m < 4; ++m)
#pragma unroll
            for (int i = 0; i < 4; ++i) {
                float s = 0.f;
#pragma unroll
                for (int n = 0; n < 4; ++n) s += acc[m][n][i] * acc[m][n][i];
                for (int off = 1; off < 16; off <<= 1) s += __shfl_xor(s, off);
                if ((lane & 15) == 0)
                    atomicAdd(&nrow[wr * 64 + m * 16 + (lane >> 4) * 4 + i], s);
            }
        __syncthreads();
        if (tid < 128) atomicAdd(&n2[i0 + tid], nrow[tid]);
    } else {
        __shared__ unsigned long long brow[128];
        if (tid < 128) brow[tid] = 0ull;
        __syncthreads();
        float njv[4];
#pragma unroll
        for (int n = 0; n < 4; ++n)
            njv[n] = sqrtf(n2[j0 + wc * 64 + n * 16 + (lane & 15)]);
#pragma unroll
        for (int m = 0; m < 4; ++m)
#pragma unroll
            for (int i = 0; i < 4; ++i) {
                int ri = i0 + wr * 64 + m * 16 + (lane >> 4) * 4 + i;
                float ni = sqrtf(n2[ri]);
                unsigned long long best = 0ull;
#pragma unroll
                for (int n = 0; n < 4; ++n) {
                    int jc = j0 + wc * 64 + n * 16 + (lane & 15);
                    if (jc < VN && jc != ri) {
                        float s = acc[m][n][i] / (ni * njv[n] + 1e-8f);
                        unsigned u = __float_as_uint(s);
                        u = (u & 0x80000000u) ? ~u : (u | 0x80000000u);
                        unsigned long long key =
                            ((unsigned long long)u << 32) | (unsigned)jc;
                        if (key > best) best = key;
                    }
                }
                for (int off = 1; off < 16; off <<= 1) {
                    unsigned long long o = __shfl_xor(best, off);
                    if (o > best) best = o;
                }
                if ((lane & 15) == 0)
                    atomicMax(&brow[wr * 64 + m * 16 + (lane >> 4) * 4 + i], best);
            }
        __syncthreads();
        if (tid < 128) atomicMax(&argbest[i0 + tid], brow[tid]);
    }
}

// ---------------- low fallback: R1 fp32 Gram ----------------
template <int PASS>
__global__ __launch_bounds__(256) void k_gemm(const float* __restrict__ E,
                                              float* __restrict__ n2,
                                              unsigned long long* __restrict__ argbest) {
    __shared__ float As[16][132];
    __shared__ float Bs[16][132];
    const int tid = threadIdx.x;
    const int tx = tid & 15, ty = tid >> 4;
    const int i0 = blockIdx.y * 128, j0 = blockIdx.x * 128;
    float acc[8][8] = {};

    for (int k0 = 0; k0 < DN; k0 += 16) {
#pragma unroll
        for (int h = 0; h < 2; ++h) {
            int f = tid + h * 256;
            int r = f >> 2;
            int kq = (f & 3) << 2;
            int gi = i0 + r;
            float4 va = make_float4(0.f, 0.f, 0.f, 0.f);
            if (gi < VN) va = *(const float4*)(E + gi * DN + k0 + kq);
            As[kq + 0][r] = va.x; As[kq + 1][r] = va.y;
            As[kq + 2][r] = va.z; As[kq + 3][r] = va.w;
            int gj = j0 + r;
            float4 vb = make_float4(0.f, 0.f, 0.f, 0.f);
            if (gj < VN) vb = *(const float4*)(E + gj * DN + k0 + kq);
            Bs[kq + 0][r] = vb.x; Bs[kq + 1][r] = vb.y;
            Bs[kq + 2][r] = vb.z; Bs[kq + 3][r] = vb.w;
        }
        __syncthreads();
#pragma unroll
        for (int k = 0; k < 16; ++k) {
            float a[8], b[8];
            *(float4*)&a[0] = *(const float4*)&As[k][ty * 8];
            *(float4*)&a[4] = *(const float4*)&As[k][ty * 8 + 4];
            *(float4*)&b[0] = *(const float4*)&Bs[k][tx * 8];
            *(float4*)&b[4] = *(const float4*)&Bs[k][tx * 8 + 4];
#pragma unroll
            for (int m = 0; m < 8; ++m)
#pragma unroll
                for (int n = 0; n < 8; ++n)
                    acc[m][n] = fmaf(a[m], b[n], acc[m][n]);
        }
        __syncthreads();
    }

    if (PASS == 0) {
        __shared__ float nrow[128];
        if (tid < 128) nrow[tid] = 0.f;
        __syncthreads();
#pragma unroll
        for (int m = 0; m < 8; ++m) {
            float s = 0.f;
#pragma unroll
            for (int n = 0; n < 8; ++n) s += acc[m][n] * acc[m][n];
            atomicAdd(&nrow[ty * 8 + m], s);
        }
        __syncthreads();
        if (tid < 128 && i0 + tid < VN) atomicAdd(&n2[i0 + tid], nrow[tid]);
    } else {
        __shared__ unsigned long long brow[128];
        if (tid < 128) brow[tid] = 0ull;
        __syncthreads();
        float njv[8];
#pragma unroll
        for (int n = 0; n < 8; ++n) {
            int j = j0 + tx * 8 + n;
            njv[n] = (j < VN) ? sqrtf(n2[j]) : 0.f;
        }
#pragma unroll
        for (int m = 0; m < 8; ++m) {
            int i = i0 + ty * 8 + m;
            float ni = (i < VN) ? sqrtf(n2[i]) : 0.f;
            unsigned long long best = 0ull;
#pragma unroll
            for (int n = 0; n < 8; ++n) {
                int j = j0 + tx * 8 + n;
                if (j < VN && j != i) {
                    float s = acc[m][n] / (ni * njv[n] + 1e-8f);
                    unsigned u = __float_as_uint(s);
                    u = (u & 0x80000000u) ? ~u : (u | 0x80000000u);
                    unsigned long long key =
                        ((unsigned long long)u << 32) | (unsigned)j;
                    if (key > best) best = key;
                }
            }
            atomicMax(&brow[ty * 8 + m], best);
        }
        __syncthreads();
        if (tid < 128 && i0 + tid < VN) atomicMax(&argbest[i0 + tid], brow[tid]);
    }
}

// ---------------- scatter + finalize ----------------
__global__ __launch_bounds__(256) void k_scatter(const float* __restrict__ pred,
                                                 const float* __restrict__ label,
                                                 const unsigned long long* __restrict__ argbest,
                                                 float* __restrict__ part2) {
    int i = blockIdx.x;
    int tid = threadIdx.x;
    __shared__ int cnt;
    __shared__ unsigned short gs[256];
    __shared__ unsigned short ts[256];
    __shared__ float ls[256];
    if (tid == 0) cnt = 0;
    __syncthreads();
    const float* lrow = label + (size_t)i * VN;
    for (int g = tid; g < VN; g += 256) {
        float l = lrow[g];
        if (l != 0.f) {
            int p = atomicAdd(&cnt, 1);
            if (p < 256) {
                gs[p] = (unsigned short)g;
                ls[p] = l;
                ts[p] = (unsigned short)(argbest[g] & 0xFFFFFFFFull);
            }
        }
    }
    __syncthreads();
    int m = min(cnt, 256);
    float contrib = 0.f;
    for (int e = tid; e < m; e += 256) {
        bool keep = true;
        for (int o = 0; o < m; ++o)
            if (ts[o] == ts[e] && gs[o] > gs[e]) keep = false;
        if (keep) contrib += pred[(size_t)i * VN + ts[e]] * ls[e];
    }
    for (int off = 32; off; off >>= 1) contrib += __shfl_down(contrib, off);
    __shared__ float wsum[4];
    int lane = tid & 63, wid = tid >> 6;
    if (lane == 0) wsum[wid] = contrib;
    __syncthreads();
    if (tid == 0) part2[i] = wsum[0] + wsum[1] + wsum[2] + wsum[3];
}

__global__ __launch_bounds__(256) void k_final(const float* __restrict__ part1,
                                               const float* __restrict__ part2,
                                               float* __restrict__ out) {
    int tid = threadIdx.x;
    double acc = 0.0;
    for (int i = tid; i < GRID_LOGEXP; i += 256) acc += (double)part1[i];
    for (int i = tid; i < BN; i += 256) acc -= (double)part2[i];
    __shared__ double red[256];
    red[tid] = acc;
    __syncthreads();
    for (int s = 128; s; s >>= 1) {
        if (tid < s) red[tid] += red[tid + s];
        __syncthreads();
    }
    if (tid == 0) out[0] = (float)(red[0] / (double)BN);
}

extern "C" void kernel_launch(void* const* d_in, const int* in_sizes, int n_in,
                              void* d_out, int out_size, void* d_ws, size_t ws_size,
                              hipStream_t stream) {
    (void)in_sizes; (void)n_in; (void)out_size;
    const float* pred  = (const float*)d_in[0];
    const float* label = (const float*)d_in[1];
    const float* E     = (const float*)d_in[2];
    float* out = (float*)d_out;
    char* wsb = (char*)d_ws;

    if (ws_size >= WS_NEEDED3) {
        unsigned short* Eb   = (unsigned short*)(wsb + WB_EB);
        unsigned short* simT = (unsigned short*)(wsb + WB_SIM);
        float* n2    = (float*)(wsb + WB_N2);
        unsigned long long* argbest = (unsigned long long*)(wsb + WB_ARG);
        float* part1 = (float*)(wsb + WB_P1);
        float* part2 = (float*)(wsb + WB_P2);

        k_zero<<<10, 256, 0, stream>>>((unsigned int*)(wsb + WB_N2), ZERO_WORDS3);
        k_prep<<<NT * DN / 8 / 256, 256, 0, stream>>>(E, Eb);
        k_logexp<<<GRID_LOGEXP, 256, 0, stream>>>(pred, part1);
        k_gsym<<<NTRI, 256, 0, stream>>>(Eb, n2, simT);
        k_argmax<<<NTRI, 256, 0, stream>>>(simT, n2, argbest);
        k_scatter<<<BN, 256, 0, stream>>>(pred, label, argbest, part2);
        k_final<<<1, 256, 0, stream>>>(part1, part2, out);
    } else if (ws_size >= WS_NEEDED2) {
        unsigned short* Eb = (unsigned short*)(wsb + W2_EB);
        float* n2    = (float*)(wsb + W2_N2);
        unsigned long long* argbest = (unsigned long long*)(wsb + W2_ARG);
        float* part1 = (float*)(wsb + W2_P1);
        float* part2 = (float*)(wsb + W2_P2);

        k_zero<<<16, 256, 0, stream>>>((unsigned int*)(wsb + W2_N2), ZERO_WORDS2);
        k_prep<<<NT * DN / 8 / 256, 256, 0, stream>>>(E, Eb);
        k_logexp<<<GRID_LOGEXP, 256, 0, stream>>>(pred, part1);
        dim3 g(NT / 128, NT / 128);
        k_mgemm<0><<<g, 256, 0, stream>>>(Eb, n2, argbest);
        k_mgemm<1><<<g, 256, 0, stream>>>(Eb, n2, argbest);
        k_scatter<<<BN, 256, 0, stream>>>(pred, label, argbest, part2);
        k_final<<<1, 256, 0, stream>>>(part1, part2, out);
    } else {
        float* ws = (float*)d_ws;
        float* n2    = ws;
        float* part1 = ws + 3136;
        float* part2 = ws + 7232;
        unsigned long long* argbest = (unsigned long long*)(ws + 9280);
        k_zero<<<16, 256, 0, stream>>>((unsigned int*)ws, 9280 + VN * 2);
        k_logexp<<<GRID_LOGEXP, 256, 0, stream>>>(pred, part1);
        dim3 g((VN + 127) / 128, (VN + 127) / 128);
        k_gemm<0><<<g, 256, 0, stream>>>(E, n2, argbest);
        k_gemm<1><<<g, 256, 0, stream>>>(E, n2, argbest);
        k_scatter<<<BN, 256, 0, stream>>>(pred, label, argbest, part2);
        k_final<<<1, 256, 0, stream>>>(part1, part2, out);
    }
}

// Round 4
// 84.752 us; speedup vs baseline: 6.4294x; 1.0673x over previous
//
#include <hip/hip_runtime.h>
#include <hip/hip_bf16.h>

#define VN 3129
#define DN 768
#define BN 2048
#define NT 3200              // VN padded to 25*128
#define NB 25                // tile blocks per side
#define NTRI 325             // NB*(NB+1)/2

typedef __attribute__((ext_vector_type(8))) short bf16x8;
typedef __attribute__((ext_vector_type(4))) float f32x4;

typedef __attribute__((address_space(3))) void as3_void;
typedef __attribute__((address_space(1))) const void as1_cvoid;

__device__ __forceinline__ void gload16(const void* g, void* l) {
    __builtin_amdgcn_global_load_lds((as1_cvoid*)g, (as3_void*)l, 16, 0, 0);
}

__device__ __forceinline__ unsigned sortable_f32(float f) {
    unsigned u = __float_as_uint(f);
    return (u & 0x80000000u) ? ~u : (u | 0x80000000u);
}

// ---------------- fast path ws layout (bytes) ----------------
// Eb      [0, 4915200)             : bf16 E padded to NT rows
// simT    [4915200, +10649600)     : bf16 tiles, 325 x 128 x 128, lane-packed
// n2      [15564800, +12800)       : float[3200]
// argbest [15577600, +12800)       : u32 packed (score20 | j12)
// part1   [15590400, +8192)        : float[2048]
// part2   [15598592, +8192)        : float[2048]
static const size_t WB_EB  = 0;
static const size_t WB_SIM = 4915200;
static const size_t WB_N2  = 15564800;
static const size_t WB_ARG = 15577600;
static const size_t WB_P1  = 15590400;
static const size_t WB_P2  = 15598592;
static const size_t WS_NEEDED3 = 15606784;
static const int ZERO_WORDS3 = 6400;      // n2 + argbest contiguous

// ---------------- mid fallback (R2) ws layout ----------------
static const size_t W2_EB  = 0;
static const size_t W2_N2  = 4915200;
static const size_t W2_ARG = 4928000;     // u32[3200]
static const size_t W2_P1  = 4940800;
static const size_t W2_P2  = 4948992;
static const size_t WS_NEEDED2 = 4957184;
static const int ZERO_WORDS2 = 6400;

static const int GRID_LOGEXP = 2048;

__global__ __launch_bounds__(256) void k_zero(unsigned int* p, int nwords) {
    int idx = blockIdx.x * 256 + threadIdx.x;
    for (int i = idx; i < nwords; i += gridDim.x * 256) p[i] = 0u;
}

__global__ __launch_bounds__(256) void k_prep(const float* __restrict__ E,
                                              unsigned short* __restrict__ Eb) {
    int chunk = blockIdx.x * 256 + threadIdx.x;   // one chunk = 8 elements
    const int nchunks = NT * DN / 8;              // 307200
    if (chunk >= nchunks) return;
    int row = chunk / (DN / 8);
    int cc = (chunk % (DN / 8)) * 8;
    unsigned short out[8];
    if (row < VN) {
        const float* src = E + (size_t)row * DN + cc;
        float4 a = *(const float4*)src;
        float4 b = *(const float4*)(src + 4);
        float v[8] = {a.x, a.y, a.z, a.w, b.x, b.y, b.z, b.w};
#pragma unroll
        for (int t = 0; t < 8; ++t) {
            unsigned u = __float_as_uint(v[t]);
            u += 0x7FFFu + ((u >> 16) & 1u);      // RNE
            out[t] = (unsigned short)(u >> 16);
        }
    } else {
#pragma unroll
        for (int t = 0; t < 8; ++t) out[t] = 0;
    }
    *(uint4*)(Eb + (size_t)chunk * 8) = *(const uint4*)out;
}

__global__ __launch_bounds__(256) void k_logexp(const float* __restrict__ pred,
                                                float* __restrict__ part1) {
    int tid = threadIdx.x;
    const float4* p4 = (const float4*)pred;
    const int n4 = BN * VN / 4;
    float acc = 0.f;
    for (int i = blockIdx.x * 256 + tid; i < n4; i += gridDim.x * 256) {
        float4 v = p4[i];
        acc += fmaxf(v.x, 0.f) + log1pf(__expf(-fabsf(v.x)));
        acc += fmaxf(v.y, 0.f) + log1pf(__expf(-fabsf(v.y)));
        acc += fmaxf(v.z, 0.f) + log1pf(__expf(-fabsf(v.z)));
        acc += fmaxf(v.w, 0.f) + log1pf(__expf(-fabsf(v.w)));
    }
    for (int off = 32; off; off >>= 1) acc += __shfl_down(acc, off);
    __shared__ float wsum[4];
    int lane = tid & 63, wid = tid >> 6;
    if (lane == 0) wsum[wid] = acc;
    __syncthreads();
    if (tid == 0) part1[blockIdx.x] = wsum[0] + wsum[1] + wsum[2] + wsum[3];
}

// ---------------- fused symmetric Gram GEMM ----------------
// One block per upper-triangle tile (bi<=bj). Computes sim tile via MFMA,
// accumulates n2 row/col sums, stores bf16 sim tile in lane-packed layout.
__global__ __launch_bounds__(256) void k_gsym(const unsigned short* __restrict__ Eb,
                                              float* __restrict__ n2,
                                              unsigned short* __restrict__ simT) {
    __shared__ __align__(16) unsigned short As[128 * 64];
    __shared__ __align__(16) unsigned short Bs[128 * 64];
    const int tid = threadIdx.x;
    const int lane = tid & 63;
    const int w = tid >> 6;
    const int wr = w >> 1, wc = w & 1;

    int t = blockIdx.x, bi = 0, rem = t;
    while (rem >= NB - bi) { rem -= NB - bi; ++bi; }
    const int bj = bi + rem;
    const int i0 = bi * 128, j0 = bj * 128;

    const int srow = lane >> 3;
    const int scol = 8 * ((lane & 7) ^ (lane >> 3));

    f32x4 acc[4][4] = {};

    for (int k0 = 0; k0 < DN; k0 += 64) {
#pragma unroll
        for (int q = 0; q < 4; ++q) {
            int ci = w * 4 + q;
            int row = ci * 8 + srow;
            gload16(Eb + (size_t)(i0 + row) * DN + k0 + scol, As + ci * 512);
            gload16(Eb + (size_t)(j0 + row) * DN + k0 + scol, Bs + ci * 512);
        }
        __syncthreads();
        const int rA = wr * 64 + (lane & 15);
        const int rB = wc * 64 + (lane & 15);
        const int swr = (lane & 7) << 4;
        const int kb = (lane >> 4) * 16;
#pragma unroll
        for (int ks = 0; ks < 2; ++ks) {
            const int cb = (kb + ks * 64) ^ swr;
            bf16x8 af[4], bfr[4];
#pragma unroll
            for (int m = 0; m < 4; ++m)
                af[m] = *(const bf16x8*)((const char*)As + (rA + m * 16) * 128 + cb);
#pragma unroll
            for (int n = 0; n < 4; ++n)
                bfr[n] = *(const bf16x8*)((const char*)Bs + (rB + n * 16) * 128 + cb);
#pragma unroll
            for (int m = 0; m < 4; ++m)
#pragma unroll
                for (int n = 0; n < 4; ++n)
                    acc[m][n] = __builtin_amdgcn_mfma_f32_16x16x32_bf16(
                        af[m], bfr[n], acc[m][n], 0, 0, 0);
        }
        __syncthreads();
    }

    // ---- n2 row sums (rows of bi-block) ----
    __shared__ float red[128];
    const int rr4 = (lane >> 4) * 4;
    if (tid < 128) red[tid] = 0.f;
    __syncthreads();
#pragma unroll
    for (int m = 0; m < 4; ++m)
#pragma unroll
        for (int i = 0; i < 4; ++i) {
            float s = 0.f;
#pragma unroll
            for (int n = 0; n < 4; ++n) { float x = acc[m][n][i]; s += x * x; }
            s += __shfl_xor(s, 1); s += __shfl_xor(s, 2);
            s += __shfl_xor(s, 4); s += __shfl_xor(s, 8);
            if ((lane & 15) == 0)
                atomicAdd(&red[wr * 64 + m * 16 + rr4 + i], s);
        }
    __syncthreads();
    if (tid < 128) atomicAdd(&n2[i0 + tid], red[tid]);
    // ---- n2 col sums (cols of bj-block), off-diagonal only ----
    if (bi != bj) {
        __syncthreads();
        if (tid < 128) red[tid] = 0.f;
        __syncthreads();
#pragma unroll
        for (int n = 0; n < 4; ++n) {
            float s = 0.f;
#pragma unroll
            for (int m = 0; m < 4; ++m)
#pragma unroll
                for (int i = 0; i < 4; ++i) { float x = acc[m][n][i]; s += x * x; }
            s += __shfl_xor(s, 16); s += __shfl_xor(s, 32);
            if (lane < 16)
                atomicAdd(&red[wc * 64 + n * 16 + lane], s);
        }
        __syncthreads();
        if (tid < 128) atomicAdd(&n2[j0 + tid], red[tid]);
    }

    // ---- store bf16 sim tile, lane-packed: tile[tid][v], v=(m*4+n)*4+i ----
    {
        unsigned short* dst = simT + (size_t)t * 16384 + (size_t)tid * 64;
        uint4 ov[8];
        unsigned* op = (unsigned*)ov;
#pragma unroll
        for (int m = 0; m < 4; ++m)
#pragma unroll
            for (int n = 0; n < 4; ++n)
#pragma unroll
                for (int ih = 0; ih < 2; ++ih) {
                    unsigned lo = __float_as_uint(acc[m][n][ih * 2]);
                    lo += 0x7FFFu + ((lo >> 16) & 1u);
                    unsigned hi = __float_as_uint(acc[m][n][ih * 2 + 1]);
                    hi += 0x7FFFu + ((hi >> 16) & 1u);
                    op[(m * 4 + n) * 2 + ih] = (lo >> 16) | (hi & 0xFFFF0000u);
                }
#pragma unroll
        for (int q = 0; q < 8; ++q) ((uint4*)dst)[q] = ov[q];
    }
}

// ---------------- argmax over stored sim tiles (u32 keys, mul-only) ----------------
__global__ __launch_bounds__(256) void k_argmax(const unsigned short* __restrict__ simT,
                                                const float* __restrict__ n2,
                                                unsigned* __restrict__ argbest) {
    const int tid = threadIdx.x, lane = tid & 63, w = tid >> 6;
    const int wr = w >> 1, wc = w & 1;
    int t = blockIdx.x, bi = 0, rem = t;
    while (rem >= NB - bi) { rem -= NB - bi; ++bi; }
    const int bj = bi + rem;
    const int i0 = bi * 128, j0 = bj * 128;

    __shared__ float rni_s[128], rnj_s[128];
    __shared__ unsigned rbest[128], cbest[128];
    if (tid < 128) {
        rni_s[tid] = rsqrtf(n2[i0 + tid]);
        rnj_s[tid] = rsqrtf(n2[j0 + tid]);
        rbest[tid] = 0u; cbest[tid] = 0u;
    }
    __syncthreads();

    const unsigned short* src = simT + (size_t)t * 16384 + (size_t)tid * 64;
    uint4 iv[8];
#pragma unroll
    for (int q = 0; q < 8; ++q) iv[q] = ((const uint4*)src)[q];
    const unsigned* ip = (const unsigned*)iv;

    const int rr4 = (lane >> 4) * 4;
    int rg[16]; float rni16[16];
#pragma unroll
    for (int m = 0; m < 4; ++m)
#pragma unroll
        for (int i = 0; i < 4; ++i) {
            int rl = wr * 64 + m * 16 + rr4 + i;
            rg[m * 4 + i] = i0 + rl;
            rni16[m * 4 + i] = rni_s[rl];
        }
    int cg[4]; float rnj4[4];
#pragma unroll
    for (int n = 0; n < 4; ++n) {
        int cl = wc * 64 + n * 16 + (lane & 15);
        cg[n] = j0 + cl;
        rnj4[n] = rnj_s[cl];
    }

    // row side: targets i in bi-block, candidates j in bj-block
#pragma unroll
    for (int m = 0; m < 4; ++m)
#pragma unroll
        for (int i = 0; i < 4; ++i) {
            int ig = rg[m * 4 + i];
            unsigned best = 0u;
#pragma unroll
            for (int n = 0; n < 4; ++n) {
                int jg = cg[n];
                if (jg < VN && jg != ig) {
                    unsigned wv = ip[(m * 4 + n) * 2 + (i >> 1)];
                    float v = __uint_as_float((i & 1) ? (wv & 0xFFFF0000u) : (wv << 16));
                    unsigned key = (sortable_f32(v * rnj4[n]) & 0xFFFFF000u) | (unsigned)jg;
                    best = max(best, key);
                }
            }
            best = max(best, __shfl_xor(best, 1));
            best = max(best, __shfl_xor(best, 2));
            best = max(best, __shfl_xor(best, 4));
            best = max(best, __shfl_xor(best, 8));
            if ((lane & 15) == 0)
                atomicMax(&rbest[wr * 64 + m * 16 + rr4 + i], best);
        }

    // col side: targets j in bj-block, candidates i in bi-block (symmetry)
    if (bi != bj) {
#pragma unroll
        for (int n = 0; n < 4; ++n) {
            unsigned best = 0u;
#pragma unroll
            for (int m = 0; m < 4; ++m)
#pragma unroll
                for (int i = 0; i < 4; ++i) {
                    int ig = rg[m * 4 + i];
                    if (ig < VN) {
                        unsigned wv = ip[(m * 4 + n) * 2 + (i >> 1)];
                        float v = __uint_as_float((i & 1) ? (wv & 0xFFFF0000u) : (wv << 16));
                        unsigned key = (sortable_f32(v * rni16[m * 4 + i]) & 0xFFFFF000u) | (unsigned)ig;
                        best = max(best, key);
                    }
                }
            best = max(best, __shfl_xor(best, 16));
            best = max(best, __shfl_xor(best, 32));
            if (lane < 16)
                atomicMax(&cbest[wc * 64 + n * 16 + lane], best);
        }
    }
    __syncthreads();
    if (tid < 128) {
        unsigned rb = rbest[tid];
        if (rb) atomicMax(&argbest[i0 + tid], rb);
        if (bi != bj) {
            unsigned cb = cbest[tid];
            if (cb) atomicMax(&argbest[j0 + tid], cb);
        }
    }
}

// ---------------- mid fallback: R2 two-pass MFMA Gram (u32 keys) ----------------
template <int PASS>
__global__ __launch_bounds__(256) void k_mgemm(const unsigned short* __restrict__ Eb,
                                               float* __restrict__ n2,
                                               unsigned* __restrict__ argbest) {
    __shared__ __align__(16) unsigned short As[128][72];
    __shared__ __align__(16) unsigned short Bs[128][72];
    const int tid = threadIdx.x;
    const int lane = tid & 63;
    const int w = tid >> 6;
    const int wr = w >> 1, wc = w & 1;
    const int i0 = blockIdx.y * 128, j0 = blockIdx.x * 128;
    const int sr = tid >> 3, sc = (tid & 7) * 8;

    f32x4 acc[4][4] = {};

    for (int k0 = 0; k0 < DN; k0 += 64) {
#pragma unroll
        for (int q = 0; q < 4; ++q) {
            int r = sr + 32 * q;
            uint4 va = *(const uint4*)(Eb + (size_t)(i0 + r) * DN + k0 + sc);
            *(uint4*)&As[r][sc] = va;
            uint4 vb = *(const uint4*)(Eb + (size_t)(j0 + r) * DN + k0 + sc);
            *(uint4*)&Bs[r][sc] = vb;
        }
        __syncthreads();
#pragma unroll
        for (int ks = 0; ks < 2; ++ks) {
            bf16x8 af[4], bfr[4];
            const int rrow = lane & 15;
            const int kcol = ks * 32 + (lane >> 4) * 8;
#pragma unroll
            for (int m = 0; m < 4; ++m)
                af[m] = *(const bf16x8*)&As[wr * 64 + m * 16 + rrow][kcol];
#pragma unroll
            for (int n = 0; n < 4; ++n)
                bfr[n] = *(const bf16x8*)&Bs[wc * 64 + n * 16 + rrow][kcol];
#pragma unroll
            for (int m = 0; m < 4; ++m)
#pragma unroll
                for (int n = 0; n < 4; ++n)
                    acc[m][n] = __builtin_amdgcn_mfma_f32_16x16x32_bf16(
                        af[m], bfr[n], acc[m][n], 0, 0, 0);
        }
        __syncthreads();
    }

    if (PASS == 0) {
        __shared__ float nrow[128];
        if (tid < 128) nrow[tid] = 0.f;
        __syncthreads();
#pragma unroll
        for (int m = 0; m < 4; ++m)
#pragma unroll
            for (int i = 0; i < 4; ++i) {
                float s = 0.f;
#pragma unroll
                for (int n = 0; n < 4; ++n) s += acc[m][n][i] * acc[m][n][i];
                for (int off = 1; off < 16; off <<= 1) s += __shfl_xor(s, off);
                if ((lane & 15) == 0)
                    atomicAdd(&nrow[wr * 64 + m * 16 + (lane >> 4) * 4 + i], s);
            }
        __syncthreads();
        if (tid < 128) atomicAdd(&n2[i0 + tid], nrow[tid]);
    } else {
        __shared__ unsigned brow[128];
        if (tid < 128) brow[tid] = 0u;
        __syncthreads();
        float rnj[4];
#pragma unroll
        for (int n = 0; n < 4; ++n)
            rnj[n] = rsqrtf(n2[j0 + wc * 64 + n * 16 + (lane & 15)]);
#pragma unroll
        for (int m = 0; m < 4; ++m)
#pragma unroll
            for (int i = 0; i < 4; ++i) {
                int ri = i0 + wr * 64 + m * 16 + (lane >> 4) * 4 + i;
                unsigned best = 0u;
#pragma unroll
                for (int n = 0; n < 4; ++n) {
                    int jc = j0 + wc * 64 + n * 16 + (lane & 15);
                    if (jc < VN && jc != ri) {
                        unsigned key = (sortable_f32(acc[m][n][i] * rnj[n]) & 0xFFFFF000u) | (unsigned)jc;
                        best = max(best, key);
                    }
                }
                for (int off = 1; off < 16; off <<= 1)
                    best = max(best, (unsigned)__shfl_xor((int)best, off));
                if ((lane & 15) == 0)
                    atomicMax(&brow[wr * 64 + m * 16 + (lane >> 4) * 4 + i], best);
            }
        __syncthreads();
        if (tid < 128) atomicMax(&argbest[i0 + tid], brow[tid]);
    }
}

// ---------------- low fallback: R1 fp32 Gram (u32 keys) ----------------
template <int PASS>
__global__ __launch_bounds__(256) void k_gemm(const float* __restrict__ E,
                                              float* __restrict__ n2,
                                              unsigned* __restrict__ argbest) {
    __shared__ float As[16][132];
    __shared__ float Bs[16][132];
    const int tid = threadIdx.x;
    const int tx = tid & 15, ty = tid >> 4;
    const int i0 = blockIdx.y * 128, j0 = blockIdx.x * 128;
    float acc[8][8] = {};

    for (int k0 = 0; k0 < DN; k0 += 16) {
#pragma unroll
        for (int h = 0; h < 2; ++h) {
            int f = tid + h * 256;
            int r = f >> 2;
            int kq = (f & 3) << 2;
            int gi = i0 + r;
            float4 va = make_float4(0.f, 0.f, 0.f, 0.f);
            if (gi < VN) va = *(const float4*)(E + gi * DN + k0 + kq);
            As[kq + 0][r] = va.x; As[kq + 1][r] = va.y;
            As[kq + 2][r] = va.z; As[kq + 3][r] = va.w;
            int gj = j0 + r;
            float4 vb = make_float4(0.f, 0.f, 0.f, 0.f);
            if (gj < VN) vb = *(const float4*)(E + gj * DN + k0 + kq);
            Bs[kq + 0][r] = vb.x; Bs[kq + 1][r] = vb.y;
            Bs[kq + 2][r] = vb.z; Bs[kq + 3][r] = vb.w;
        }
        __syncthreads();
#pragma unroll
        for (int k = 0; k < 16; ++k) {
            float a[8], b[8];
            *(float4*)&a[0] = *(const float4*)&As[k][ty * 8];
            *(float4*)&a[4] = *(const float4*)&As[k][ty * 8 + 4];
            *(float4*)&b[0] = *(const float4*)&Bs[k][tx * 8];
            *(float4*)&b[4] = *(const float4*)&Bs[k][tx * 8 + 4];
#pragma unroll
            for (int m = 0; m < 8; ++m)
#pragma unroll
                for (int n = 0; n < 8; ++n)
                    acc[m][n] = fmaf(a[m], b[n], acc[m][n]);
        }
        __syncthreads();
    }

    if (PASS == 0) {
        __shared__ float nrow[128];
        if (tid < 128) nrow[tid] = 0.f;
        __syncthreads();
#pragma unroll
        for (int m = 0; m < 8; ++m) {
            float s = 0.f;
#pragma unroll
            for (int n = 0; n < 8; ++n) s += acc[m][n] * acc[m][n];
            atomicAdd(&nrow[ty * 8 + m], s);
        }
        __syncthreads();
        if (tid < 128 && i0 + tid < VN) atomicAdd(&n2[i0 + tid], nrow[tid]);
    } else {
        __shared__ unsigned brow[128];
        if (tid < 128) brow[tid] = 0u;
        __syncthreads();
        float rnj[8];
#pragma unroll
        for (int n = 0; n < 8; ++n) {
            int j = j0 + tx * 8 + n;
            rnj[n] = (j < VN) ? rsqrtf(n2[j]) : 0.f;
        }
#pragma unroll
        for (int m = 0; m < 8; ++m) {
            int i = i0 + ty * 8 + m;
            unsigned best = 0u;
#pragma unroll
            for (int n = 0; n < 8; ++n) {
                int j = j0 + tx * 8 + n;
                if (j < VN && j != i) {
                    unsigned key = (sortable_f32(acc[m][n] * rnj[n]) & 0xFFFFF000u) | (unsigned)j;
                    best = max(best, key);
                }
            }
            atomicMax(&brow[ty * 8 + m], best);
        }
        __syncthreads();
        if (tid < 128 && i0 + tid < VN) atomicMax(&argbest[i0 + tid], brow[tid]);
    }
}

// ---------------- scatter + finalize ----------------
__global__ __launch_bounds__(256) void k_scatter(const float* __restrict__ pred,
                                                 const float* __restrict__ label,
                                                 const unsigned* __restrict__ argbest,
                                                 float* __restrict__ part2) {
    int i = blockIdx.x;
    int tid = threadIdx.x;
    __shared__ int cnt;
    __shared__ unsigned short gs[256];
    __shared__ unsigned short ts[256];
    __shared__ float ls[256];
    if (tid == 0) cnt = 0;
    __syncthreads();
    const float* lrow = label + (size_t)i * VN;
    for (int g = tid; g < VN; g += 256) {
        float l = lrow[g];
        if (l != 0.f) {
            int p = atomicAdd(&cnt, 1);
            if (p < 256) {
                gs[p] = (unsigned short)g;
                ls[p] = l;
                ts[p] = (unsigned short)(argbest[g] & 0xFFFu);
            }
        }
    }
    __syncthreads();
    int m = min(cnt, 256);
    float contrib = 0.f;
    for (int e = tid; e < m; e += 256) {
        bool keep = true;
        for (int o = 0; o < m; ++o)
            if (ts[o] == ts[e] && gs[o] > gs[e]) keep = false;
        if (keep) contrib += pred[(size_t)i * VN + ts[e]] * ls[e];
    }
    for (int off = 32; off; off >>= 1) contrib += __shfl_down(contrib, off);
    __shared__ float wsum[4];
    int lane = tid & 63, wid = tid >> 6;
    if (lane == 0) wsum[wid] = contrib;
    __syncthreads();
    if (tid == 0) part2[i] = wsum[0] + wsum[1] + wsum[2] + wsum[3];
}

__global__ __launch_bounds__(256) void k_final(const float* __restrict__ part1,
                                               const float* __restrict__ part2,
                                               float* __restrict__ out) {
    int tid = threadIdx.x;
    double acc = 0.0;
    for (int i = tid; i < GRID_LOGEXP; i += 256) acc += (double)part1[i];
    for (int i = tid; i < BN; i += 256) acc -= (double)part2[i];
    __shared__ double red[256];
    red[tid] = acc;
    __syncthreads();
    for (int s = 128; s; s >>= 1) {
        if (tid < s) red[tid] += red[tid + s];
        __syncthreads();
    }
    if (tid == 0) out[0] = (float)(red[0] / (double)BN);
}

extern "C" void kernel_launch(void* const* d_in, const int* in_sizes, int n_in,
                              void* d_out, int out_size, void* d_ws, size_t ws_size,
                              hipStream_t stream) {
    (void)in_sizes; (void)n_in; (void)out_size;
    const float* pred  = (const float*)d_in[0];
    const float* label = (const float*)d_in[1];
    const float* E     = (const float*)d_in[2];
    float* out = (float*)d_out;
    char* wsb = (char*)d_ws;

    if (ws_size >= WS_NEEDED3) {
        unsigned short* Eb   = (unsigned short*)(wsb + WB_EB);
        unsigned short* simT = (unsigned short*)(wsb + WB_SIM);
        float* n2    = (float*)(wsb + WB_N2);
        unsigned* argbest = (unsigned*)(wsb + WB_ARG);
        float* part1 = (float*)(wsb + WB_P1);
        float* part2 = (float*)(wsb + WB_P2);

        k_zero<<<10, 256, 0, stream>>>((unsigned int*)(wsb + WB_N2), ZERO_WORDS3);
        k_prep<<<NT * DN / 8 / 256, 256, 0, stream>>>(E, Eb);
        k_logexp<<<GRID_LOGEXP, 256, 0, stream>>>(pred, part1);
        k_gsym<<<NTRI, 256, 0, stream>>>(Eb, n2, simT);
        k_argmax<<<NTRI, 256, 0, stream>>>(simT, n2, argbest);
        k_scatter<<<BN, 256, 0, stream>>>(pred, label, argbest, part2);
        k_final<<<1, 256, 0, stream>>>(part1, part2, out);
    } else if (ws_size >= WS_NEEDED2) {
        unsigned short* Eb = (unsigned short*)(wsb + W2_EB);
        float* n2    = (float*)(wsb + W2_N2);
        unsigned* argbest = (unsigned*)(wsb + W2_ARG);
        float* part1 = (float*)(wsb + W2_P1);
        float* part2 = (float*)(wsb + W2_P2);

        k_zero<<<10, 256, 0, stream>>>((unsigned int*)(wsb + W2_N2), ZERO_WORDS2);
        k_prep<<<NT * DN / 8 / 256, 256, 0, stream>>>(E, Eb);
        k_logexp<<<GRID_LOGEXP, 256, 0, stream>>>(pred, part1);
        dim3 g(NT / 128, NT / 128);
        k_mgemm<0><<<g, 256, 0, stream>>>(Eb, n2, argbest);
        k_mgemm<1><<<g, 256, 0, stream>>>(Eb, n2, argbest);
        k_scatter<<<BN, 256, 0, stream>>>(pred, label, argbest, part2);
        k_final<<<1, 256, 0, stream>>>(part1, part2, out);
    } else {
        float* ws = (float*)d_ws;
        float* n2    = ws;                       // 3200 words
        unsigned* argbest = (unsigned*)(ws + 3200);  // 3200 words
        float* part1 = ws + 6400;
        float* part2 = ws + 8448;
        k_zero<<<10, 256, 0, stream>>>((unsigned int*)ws, 6400);
        k_logexp<<<GRID_LOGEXP, 256, 0, stream>>>(pred, part1);
        dim3 g((VN + 127) / 128, (VN + 127) / 128);
        k_gemm<0><<<g, 256, 0, stream>>>(E, n2, argbest);
        k_gemm<1><<<g, 256, 0, stream>>>(E, n2, argbest);
        k_scatter<<<BN, 256, 0, stream>>>(pred, label, argbest, part2);
        k_final<<<1, 256, 0, stream>>>(part1, part2, out);
    }
}